// Round 2
// baseline (449.182 us; speedup 1.0000x reference)
//
#include <hip/hip_runtime.h>
#include <math.h>

#define N_HI 192      // IMAGE_RES_OUT * IMAGE_UPSCALE
#define F_HI 128      // FREQ_RES_OUT * FREQ_UPSCALE
#define NOUT 96
#define FOUT 32
#define GUARD 32
#define ACCW (F_HI + 2*GUARD)   // 192: guarded accumulator width
#define MAXP 194                // 192 survivors max + dummy + pad

__device__ __forceinline__ float fast_exp2(float x) {
#if __has_builtin(__builtin_amdgcn_exp2f)
    return __builtin_amdgcn_exp2f(x);
#else
    return exp2f(x);
#endif
}

__global__ __launch_bounds__(256) void cube_sim_kernel(
    const float* __restrict__ p_inc, const float* __restrict__ p_rot,
    const float* __restrict__ p_lb,  const float* __restrict__ p_vs,
    const float* __restrict__ p_vmax,const float* __restrict__ p_rc,
    const float* __restrict__ p_Rd,  const float* __restrict__ p_hz,
    const float* __restrict__ freqs, float* __restrict__ out)
{
    const int jo   = blockIdx.x;
    const int io   = blockIdx.y;
    const int tid  = threadIdx.x;
    const int col  = tid >> 6;        // wave id = column in the 2x2 hi-res patch
    const int lane = tid & 63;
    const int half = lane >> 5;       // survivor parity this lane serves
    const int sub  = lane & 31;       // channel offset slot within window

    __shared__ float2 pairs[4][MAXP];       // compacted (v_los, log2 I)
    __shared__ float  acc[4][2][ACCW];      // per-column even/odd channel accums

    // ---- uniform scalar setup ----
    const float FOV    = 500.0f;
    const float C_KMS  = 299792.458f;
    const float F_REST = 230.538f;
    const float LOG2E  = 1.4426950408889634f;

    const float inc    = *p_inc;
    const float rot    = *p_rot;
    const float lb     = *p_lb;
    const float vshift = *p_vs;
    const float vmax   = *p_vmax;
    const float rc     = *p_rc;
    const float Rd     = *p_Rd;
    const float hz     = *p_hz;
    const float f0     = freqs[0];
    const float f_last = freqs[FOUT - 1];

    const float cr = cosf(rot), sr = sinf(rot);
    const float ci = cosf(inc), si = sinf(inc);

    const float dx     = 2.0f * FOV / (float)(N_HI - 1);
    const float Rmin   = 0.1f * (2.0f * FOV / (float)N_HI);
    const float rc2pm  = rc * rc + Rmin * Rmin;
    const float sig_sq = lb * lb;
    const float nc2    = -(0.5f / sig_sq) * LOG2E;    // Gaussian exponent coeff (log2)
    const float kR     = LOG2E / Rd;                  // intensity radial coeff (log2)
    const float kz     = 0.5f * LOG2E / (hz * hz);    // intensity vertical coeff (log2)
    const float THR_L  = -19.93f;                     // log2(1e-6): survivor cutoff

    const float fstep = (f_last - f0) / (float)(F_HI - 1);
    const float vlA   = C_KMS * (1.0f - f0 / F_REST) - vshift;  // vlab(0)
    const float vlB   = -C_KMS * fstep / F_REST;                // vlab step / channel
    const float invB  = 1.0f / vlB;
    const float cA    = -vlA * invB;                            // fc = vl*invB + cA

    // ---- zero this wave's accumulators (wave-private, no barrier needed) ----
    {
        float* a = &acc[col][0][0];
        #pragma unroll
        for (int t = 0; t < 2 * ACCW / 64; ++t) a[t * 64 + lane] = 0.0f;
    }

    // ---- phase 1: column voxels -> compacted (v_los, log2 I) via ballot ----
    const int i = (io << 1) + (col >> 1);
    const int j = (jo << 1) + (col & 1);
    const float x  = -FOV + dx * (float)i;
    const float y  = -FOV + dx * (float)j;
    const float rx = cr * x - sr * y;          // z-independent
    const float y1 = sr * x + cr * y;
    const float ciy1 = ci * y1, siy1 = si * y1;
    const float nsvrx = -si * vmax * rx;
    const float rx2c  = rx * rx + rc2pm;
    const unsigned long long lmask = (lane == 63) ? ~0ull >> 1 : (1ull << lane) - 1ull;

    int cnt = 0;
    #pragma unroll
    for (int c = 0; c < 3; ++c) {
        const float z  = -FOV + dx * (float)(c * 64 + lane);
        const float ry = ciy1 - si * z;
        const float rz = siy1 + ci * z;
        const float ry2 = ry * ry;
        const float R  = sqrtf(rx * rx + ry2);
        const float L  = -(R * kR + rz * rz * kz);   // log2 intensity
        const bool pred = (L >= THR_L);
        const unsigned long long mask = __ballot(pred);
        if (pred) {
            const float inv = __frsqrt_rn(ry2 + rx2c);
            const int pos = cnt + __popcll(mask & ((1ull << lane) - 1ull));
            pairs[col][pos] = make_float2(nsvrx * inv, L);
        }
        cnt += __popcll(mask);
    }
    if (lane == 0) pairs[col][cnt] = make_float2(0.0f, -100000.0f); // dead pad
    const int npair = (cnt + 1) >> 1;

    // ---- phase 2: windowed Gaussian scatter, 2 survivors per wave-iter ----
    const float cLane = vlA + vlB * (float)(sub - 15);  // vlab at offset slot
    float* accp = &acc[col][half][0];
    const int addrc = sub - 15 + GUARD;
    for (int it = 0; it < npair; ++it) {
        const float2 p = pairs[col][2 * it + half];
        const float vl = p.x, L = p.y;
        const float fc = fmaf(vl, invB, cA);       // center channel (float)
        int ic = (int)fc;
        ic = min(max(ic, -17), 143);               // keep scatter in-guard
        const float ff = (float)ic;
        const float t  = cLane - vl;
        const float d  = fmaf(ff, vlB, t);         // vlab(ic+sub-15) - vl
        const float w  = fast_exp2(fmaf(d * d, nc2, L));
        atomicAdd(&accp[ic + addrc], w);           // all 64 addrs distinct
    }
    __syncthreads();

    // ---- phase 3: fold 4 cols x 2 halves x 4 freq-subchannels -> 32 outputs ----
    if (tid < FOUT) {
        float s = 0.0f;
        #pragma unroll
        for (int c2 = 0; c2 < 4; ++c2)
            #pragma unroll
            for (int h = 0; h < 2; ++h)
                #pragma unroll
                for (int fu = 0; fu < 4; ++fu)
                    s += acc[c2][h][GUARD + 4 * tid + fu];
        const float norm16 = (1.0f / sqrtf(2.0f * 3.14159265358979f * sig_sq)) / 16.0f;
        out[tid * (NOUT * NOUT) + io * NOUT + jo] = s * norm16;
    }
}

extern "C" void kernel_launch(void* const* d_in, const int* in_sizes, int n_in,
                              void* d_out, int out_size, void* d_ws, size_t ws_size,
                              hipStream_t stream) {
    const float* p_inc  = (const float*)d_in[0];
    const float* p_rot  = (const float*)d_in[1];
    const float* p_lb   = (const float*)d_in[2];
    const float* p_vs   = (const float*)d_in[3];
    const float* p_vmax = (const float*)d_in[4];
    const float* p_rc   = (const float*)d_in[5];
    const float* p_Rd   = (const float*)d_in[6];
    const float* p_hz   = (const float*)d_in[7];
    const float* freqs  = (const float*)d_in[8];
    float* out = (float*)d_out;

    dim3 grid(NOUT, NOUT);
    dim3 block(256);
    cube_sim_kernel<<<grid, block, 0, stream>>>(p_inc, p_rot, p_lb, p_vs,
                                                p_vmax, p_rc, p_Rd, p_hz,
                                                freqs, out);
}

// Round 3
// 61.588 us; speedup vs baseline: 7.2934x; 7.2934x over previous
//
#include <hip/hip_runtime.h>
#include <math.h>

#define N_HI 192      // IMAGE_RES_OUT * IMAGE_UPSCALE
#define F_HI 128      // FREQ_RES_OUT * FREQ_UPSCALE
#define NOUT 96
#define FOUT 32
#define MAXP 196      // 192 survivors max + 2 dead pads (float4-read safe)

__device__ __forceinline__ float fast_exp2(float x) {
#if __has_builtin(__builtin_amdgcn_exp2f)
    return __builtin_amdgcn_exp2f(x);
#else
    return exp2f(x);
#endif
}

__global__ __launch_bounds__(256) void cube_sim_kernel(
    const float* __restrict__ p_inc, const float* __restrict__ p_rot,
    const float* __restrict__ p_lb,  const float* __restrict__ p_vs,
    const float* __restrict__ p_vmax,const float* __restrict__ p_rc,
    const float* __restrict__ p_Rd,  const float* __restrict__ p_hz,
    const float* __restrict__ freqs, float* __restrict__ out)
{
    const int jo   = blockIdx.x;
    const int io   = blockIdx.y;
    const int tid  = threadIdx.x;
    const int col  = tid >> 6;        // wave id = column in the 2x2 hi-res patch
    const int lane = tid & 63;

    __shared__ float2 pairs[4][MAXP];   // compacted (v_los, log2 I), wave-private
    __shared__ float  acc_s[4][F_HI];

    // ---- uniform scalar setup ----
    const float FOV    = 500.0f;
    const float C_KMS  = 299792.458f;
    const float F_REST = 230.538f;
    const float LOG2E  = 1.4426950408889634f;

    const float inc    = *p_inc;
    const float rot    = *p_rot;
    const float lb     = *p_lb;
    const float vshift = *p_vs;
    const float vmax   = *p_vmax;
    const float rc     = *p_rc;
    const float Rd     = *p_Rd;
    const float hz     = *p_hz;
    const float f0     = freqs[0];
    const float f_last = freqs[FOUT - 1];

    const float cr = cosf(rot), sr = sinf(rot);
    const float ci = cosf(inc), si = sinf(inc);

    const float dx     = 2.0f * FOV / (float)(N_HI - 1);
    const float Rmin   = 0.1f * (2.0f * FOV / (float)N_HI);
    const float rc2pm  = rc * rc + Rmin * Rmin;
    const float sig_sq = lb * lb;
    const float nc2    = -(0.5f / sig_sq) * LOG2E;    // Gaussian exponent coeff (log2)
    const float kR     = LOG2E / Rd;                  // intensity radial coeff (log2)
    const float kz     = 0.5f * LOG2E / (hz * hz);    // intensity vertical coeff (log2)
    const float THR_L  = -19.93f;                     // log2(1e-6): survivor cutoff

    const float fstep = (f_last - f0) / (float)(F_HI - 1);
    const float vlA   = C_KMS * (1.0f - f0 / F_REST) - vshift;  // vlab(0)
    const float vlB   = -C_KMS * fstep / F_REST;                // vlab step / channel
    const float Dv    = 64.0f * vlB;                            // channel-64 offset
    const float c3    = 2.0f * Dv * nc2;                        // delta-arg coeffs
    const float c4    = Dv * Dv * nc2;

    // ---- phase 1: column voxels -> compacted (v_los, log2 I) via ballot ----
    const int i = (io << 1) + (col >> 1);
    const int j = (jo << 1) + (col & 1);
    const float x  = -FOV + dx * (float)i;
    const float y  = -FOV + dx * (float)j;
    const float rx = cr * x - sr * y;          // z-independent
    const float y1 = sr * x + cr * y;
    const float ciy1 = ci * y1, siy1 = si * y1;
    const float nsvrx = -si * vmax * rx;
    const float rx2c  = rx * rx + rc2pm;

    int cnt = 0;
    #pragma unroll
    for (int c = 0; c < 3; ++c) {
        const float z  = -FOV + dx * (float)(c * 64 + lane);
        const float ry = ciy1 - si * z;
        const float rz = siy1 + ci * z;
        const float ry2 = ry * ry;
        const float R  = sqrtf(rx * rx + ry2);
        const float L  = -(R * kR + rz * rz * kz);   // log2 intensity
        const bool pred = (L >= THR_L);
        const unsigned long long mask = __ballot(pred);
        if (pred) {
            const float inv = __frsqrt_rn(ry2 + rx2c);
            const int pos = cnt + __popcll(mask & ((1ull << lane) - 1ull));
            pairs[col][pos] = make_float2(nsvrx * inv, L);
        }
        cnt += __popcll(mask);
    }
    if (lane < 2)   // two dead pads so the float4 read of the last pair is safe
        pairs[col][cnt + lane] = make_float2(0.0f, -100000.0f);
    const int nIter = (cnt + 1) >> 1;

    // ---- phase 2: 2 survivors/iter, lane owns channels {lane, lane+64} ----
    const float vlab0 = vlA + vlB * (float)lane;
    float a0 = 0.0f, a1 = 0.0f;
    const float4* pp = reinterpret_cast<const float4*>(&pairs[col][0]);
    for (int it = 0; it < nIter; ++it) {
        const float4 q = pp[it];                 // wave-uniform broadcast b128
        // survivor A
        {
            const float d0   = vlab0 - q.x;
            const float arg0 = __builtin_fmaf(d0, d0 * nc2, q.y);
            const float arg1 = arg0 + __builtin_fmaf(d0, c3, c4);
            a0 += fast_exp2(arg0);
            a1 += fast_exp2(arg1);
        }
        // survivor B
        {
            const float d0   = vlab0 - q.z;
            const float arg0 = __builtin_fmaf(d0, d0 * nc2, q.w);
            const float arg1 = arg0 + __builtin_fmaf(d0, c3, c4);
            a0 += fast_exp2(arg0);
            a1 += fast_exp2(arg1);
        }
    }
    acc_s[col][lane]      = a0;
    acc_s[col][lane + 64] = a1;
    __syncthreads();

    // ---- phase 3: fold 4 cols x 4 freq-subchannels -> 32 outputs ----
    if (tid < FOUT) {
        float s = 0.0f;
        #pragma unroll
        for (int fu = 0; fu < 4; ++fu)
            #pragma unroll
            for (int c2 = 0; c2 < 4; ++c2)
                s += acc_s[c2][4 * tid + fu];
        const float norm16 = (1.0f / sqrtf(2.0f * 3.14159265358979f * sig_sq)) / 16.0f;
        out[tid * (NOUT * NOUT) + io * NOUT + jo] = s * norm16;
    }
}

extern "C" void kernel_launch(void* const* d_in, const int* in_sizes, int n_in,
                              void* d_out, int out_size, void* d_ws, size_t ws_size,
                              hipStream_t stream) {
    const float* p_inc  = (const float*)d_in[0];
    const float* p_rot  = (const float*)d_in[1];
    const float* p_lb   = (const float*)d_in[2];
    const float* p_vs   = (const float*)d_in[3];
    const float* p_vmax = (const float*)d_in[4];
    const float* p_rc   = (const float*)d_in[5];
    const float* p_Rd   = (const float*)d_in[6];
    const float* p_hz   = (const float*)d_in[7];
    const float* freqs  = (const float*)d_in[8];
    float* out = (float*)d_out;

    dim3 grid(NOUT, NOUT);
    dim3 block(256);
    cube_sim_kernel<<<grid, block, 0, stream>>>(p_inc, p_rot, p_lb, p_vs,
                                                p_vmax, p_rc, p_Rd, p_hz,
                                                freqs, out);
}

// Round 4
// 58.987 us; speedup vs baseline: 7.6149x; 1.0441x over previous
//
#include <hip/hip_runtime.h>
#include <math.h>

#define N_HI 192      // IMAGE_RES_OUT * IMAGE_UPSCALE
#define F_HI 128      // FREQ_RES_OUT * FREQ_UPSCALE
#define NOUT 96
#define FOUT 32
#define MAXP 196      // 192 survivors max + 2 dead pads (float4-read safe)

__device__ __forceinline__ float fast_exp2(float x) {
#if __has_builtin(__builtin_amdgcn_exp2f)
    return __builtin_amdgcn_exp2f(x);
#else
    return exp2f(x);
#endif
}

__global__ __launch_bounds__(256) void cube_sim_kernel(
    const float* __restrict__ p_inc, const float* __restrict__ p_rot,
    const float* __restrict__ p_lb,  const float* __restrict__ p_vs,
    const float* __restrict__ p_vmax,const float* __restrict__ p_rc,
    const float* __restrict__ p_Rd,  const float* __restrict__ p_hz,
    const float* __restrict__ freqs, float* __restrict__ out)
{
    const int jo   = blockIdx.x;
    const int io   = blockIdx.y;
    const int tid  = threadIdx.x;
    const int col  = tid >> 6;        // wave id = column in the 2x2 hi-res patch
    const int lane = tid & 63;

    __shared__ float2 pairs[4][MAXP];            // compacted (v_los, log2 I)
    __shared__ unsigned char cls_s[4][MAXP];     // per-survivor class {0,1,2}
    __shared__ float  acc_s[4][F_HI];

    // ---- uniform scalar setup ----
    const float FOV    = 500.0f;
    const float C_KMS  = 299792.458f;
    const float F_REST = 230.538f;
    const float LOG2E  = 1.4426950408889634f;

    const float inc    = *p_inc;
    const float rot    = *p_rot;
    const float lb     = *p_lb;
    const float vshift = *p_vs;
    const float vmax   = *p_vmax;
    const float rc     = *p_rc;
    const float Rd     = *p_Rd;
    const float hz     = *p_hz;
    const float f0     = freqs[0];
    const float f_last = freqs[FOUT - 1];

    const float cr = cosf(rot), sr = sinf(rot);
    const float ci = cosf(inc), si = sinf(inc);

    const float dx     = 2.0f * FOV / (float)(N_HI - 1);
    const float Rmin   = 0.1f * (2.0f * FOV / (float)N_HI);
    const float rc2pm  = rc * rc + Rmin * Rmin;
    const float sig_sq = lb * lb;
    const float nc2    = -(0.5f / sig_sq) * LOG2E;    // Gaussian exponent coeff (log2)
    const float kR     = LOG2E / Rd;                  // intensity radial coeff (log2)
    const float kz     = 0.5f * LOG2E / (hz * hz);    // intensity vertical coeff (log2)
    const float THR_L  = -16.61f;                     // log2(1e-5): survivor cutoff

    const float fstep = (f_last - f0) / (float)(F_HI - 1);
    const float vlA   = C_KMS * (1.0f - f0 / F_REST) - vshift;  // vlab(0)
    const float vlB   = -C_KMS * fstep / F_REST;                // vlab step / channel
    const float Dv    = 64.0f * vlB;                            // channel-64 offset
    const float c3    = 2.0f * Dv * nc2;                        // delta-arg coeffs
    const float c4    = Dv * Dv * nc2;
    const float invB  = 1.0f / vlB;
    const float cA    = -vlA * invB;                            // fc = vl*invB + cA
    // half-skip classification thresholds (5.5 sigma margin, in channel units)
    const float margin = 5.5f * lb * fabsf(invB);
    const float T0 = 64.0f - margin;   // fc <= T0  -> upper half negligible (class 0)
    const float T1 = 63.0f + margin;   // fc >= T1  -> lower half negligible (class 1)

    // ---- phase 1: column voxels -> compacted (v_los, log2 I, class) ----
    const int i = (io << 1) + (col >> 1);
    const int j = (jo << 1) + (col & 1);
    const float x  = -FOV + dx * (float)i;
    const float y  = -FOV + dx * (float)j;
    const float rx = cr * x - sr * y;          // z-independent
    const float y1 = sr * x + cr * y;
    const float ciy1 = ci * y1, siy1 = si * y1;
    const float nsvrx = -si * vmax * rx;
    const float rx2c  = rx * rx + rc2pm;

    int cnt = 0;
    #pragma unroll
    for (int c = 0; c < 3; ++c) {
        const float z  = -FOV + dx * (float)(c * 64 + lane);
        const float ry = ciy1 - si * z;
        const float rz = siy1 + ci * z;
        const float ry2 = ry * ry;
        const float R  = sqrtf(rx * rx + ry2);
        const float L  = -(R * kR + rz * rz * kz);   // log2 intensity
        const bool pred = (L >= THR_L);
        const unsigned long long mask = __ballot(pred);
        if (pred) {
            const float inv  = __frsqrt_rn(ry2 + rx2c);
            const float vlos = nsvrx * inv;
            const float fc   = __builtin_fmaf(vlos, invB, cA);
            int cls = 2;
            if (fc <= T0) cls = 0; else if (fc >= T1) cls = 1;
            const int pos = cnt + __popcll(mask & ((1ull << lane) - 1ull));
            pairs[col][pos] = make_float2(vlos, L);
            cls_s[col][pos] = (unsigned char)cls;
        }
        cnt += __popcll(mask);
    }
    if (lane < 2) {  // dead pads: float4 read of last pair is safe, class 0
        pairs[col][cnt + lane] = make_float2(0.0f, -100000.0f);
        cls_s[col][cnt + lane] = 0;
    }
    const int nIter = (cnt + 1) >> 1;

    // ---- phase 2: 2 survivors/iter, lane owns channels {lane, lane+64} ----
    const float vlab0 = vlA + vlB * (float)lane;
    const float vlab1 = vlA + vlB * (float)(lane + 64);
    float a0 = 0.0f, a1 = 0.0f;
    const float4* pp = reinterpret_cast<const float4*>(&pairs[col][0]);
    const unsigned short* cp = reinterpret_cast<const unsigned short*>(&cls_s[col][0]);
    for (int it = 0; it < nIter; ++it) {
        const float4 q = pp[it];                 // wave-uniform broadcast b128
        const int cc = __builtin_amdgcn_readfirstlane((int)cp[it]);
        if (cc == 0) {
            // both survivors: support entirely in lower half -> a0 only
            const float dA = vlab0 - q.x;
            const float dB = vlab0 - q.z;
            a0 += fast_exp2(__builtin_fmaf(dA, dA * nc2, q.y));
            a0 += fast_exp2(__builtin_fmaf(dB, dB * nc2, q.w));
        } else if (cc == 0x0101) {
            // both survivors: support entirely in upper half -> a1 only
            const float dA = vlab1 - q.x;
            const float dB = vlab1 - q.z;
            a1 += fast_exp2(__builtin_fmaf(dA, dA * nc2, q.y));
            a1 += fast_exp2(__builtin_fmaf(dB, dB * nc2, q.w));
        } else {
            // full evaluation (mixed or straddling pairs)
            {
                const float d0   = vlab0 - q.x;
                const float arg0 = __builtin_fmaf(d0, d0 * nc2, q.y);
                const float arg1 = arg0 + __builtin_fmaf(d0, c3, c4);
                a0 += fast_exp2(arg0);
                a1 += fast_exp2(arg1);
            }
            {
                const float d0   = vlab0 - q.z;
                const float arg0 = __builtin_fmaf(d0, d0 * nc2, q.w);
                const float arg1 = arg0 + __builtin_fmaf(d0, c3, c4);
                a0 += fast_exp2(arg0);
                a1 += fast_exp2(arg1);
            }
        }
    }
    acc_s[col][lane]      = a0;
    acc_s[col][lane + 64] = a1;
    __syncthreads();

    // ---- phase 3: fold 4 cols x 4 freq-subchannels -> 32 outputs ----
    if (tid < FOUT) {
        float s = 0.0f;
        #pragma unroll
        for (int fu = 0; fu < 4; ++fu)
            #pragma unroll
            for (int c2 = 0; c2 < 4; ++c2)
                s += acc_s[c2][4 * tid + fu];
        const float norm16 = (1.0f / sqrtf(2.0f * 3.14159265358979f * sig_sq)) / 16.0f;
        out[tid * (NOUT * NOUT) + io * NOUT + jo] = s * norm16;
    }
}

extern "C" void kernel_launch(void* const* d_in, const int* in_sizes, int n_in,
                              void* d_out, int out_size, void* d_ws, size_t ws_size,
                              hipStream_t stream) {
    const float* p_inc  = (const float*)d_in[0];
    const float* p_rot  = (const float*)d_in[1];
    const float* p_lb   = (const float*)d_in[2];
    const float* p_vs   = (const float*)d_in[3];
    const float* p_vmax = (const float*)d_in[4];
    const float* p_rc   = (const float*)d_in[5];
    const float* p_Rd   = (const float*)d_in[6];
    const float* p_hz   = (const float*)d_in[7];
    const float* freqs  = (const float*)d_in[8];
    float* out = (float*)d_out;

    dim3 grid(NOUT, NOUT);
    dim3 block(256);
    cube_sim_kernel<<<grid, block, 0, stream>>>(p_inc, p_rot, p_lb, p_vs,
                                                p_vmax, p_rc, p_Rd, p_hz,
                                                freqs, out);
}

// Round 5
// 45.866 us; speedup vs baseline: 9.7934x; 1.2861x over previous
//
#include <hip/hip_runtime.h>
#include <math.h>

#define N_HI 192      // IMAGE_RES_OUT * IMAGE_UPSCALE
#define F_HI 128      // FREQ_RES_OUT * FREQ_UPSCALE
#define NOUT 96
#define FOUT 32
#define NB   6        // 5 window buckets + 1 full-eval fallback
#define MAXP 212      // 192 survivors + 6*2 pads + alignment slack

__device__ __forceinline__ float fast_exp2(float x) {
#if __has_builtin(__builtin_amdgcn_exp2f)
    return __builtin_amdgcn_exp2f(x);
#else
    return exp2f(x);
#endif
}

__global__ __launch_bounds__(256) void cube_sim_kernel(
    const float* __restrict__ p_inc, const float* __restrict__ p_rot,
    const float* __restrict__ p_lb,  const float* __restrict__ p_vs,
    const float* __restrict__ p_vmax,const float* __restrict__ p_rc,
    const float* __restrict__ p_Rd,  const float* __restrict__ p_hz,
    const float* __restrict__ freqs, float* __restrict__ out)
{
    const int jo   = blockIdx.x;
    const int io   = blockIdx.y;
    const int tid  = threadIdx.x;
    const int col  = tid >> 6;        // wave id = column in the 2x2 hi-res patch
    const int lane = tid & 63;

    __shared__ alignas(16) float2 pairs[4][MAXP];  // bucket-segmented (v_los, log2 I)
    __shared__ float acc_s[4][F_HI];               // wave-private channel accumulators

    // ---- uniform scalar setup ----
    const float FOV    = 500.0f;
    const float C_KMS  = 299792.458f;
    const float F_REST = 230.538f;
    const float LOG2E  = 1.4426950408889634f;

    const float inc    = *p_inc;
    const float rot    = *p_rot;
    const float lb     = *p_lb;
    const float vshift = *p_vs;
    const float vmax   = *p_vmax;
    const float rc     = *p_rc;
    const float Rd     = *p_Rd;
    const float hz     = *p_hz;
    const float f0     = freqs[0];
    const float f_last = freqs[FOUT - 1];

    const float cr = cosf(rot), sr = sinf(rot);
    const float ci = cosf(inc), si = sinf(inc);

    const float dx     = 2.0f * FOV / (float)(N_HI - 1);
    const float Rmin   = 0.1f * (2.0f * FOV / (float)N_HI);
    const float rc2pm  = rc * rc + Rmin * Rmin;
    const float sig_sq = lb * lb;
    const float nc2    = -(0.5f / sig_sq) * LOG2E;    // Gaussian exponent coeff (log2)
    const float kR     = LOG2E / Rd;                  // intensity radial coeff (log2)
    const float kz     = 0.5f * LOG2E / (hz * hz);    // intensity vertical coeff (log2)
    const float THR_L  = -16.61f;                     // log2(1e-5): survivor cutoff

    const float fstep = (f_last - f0) / (float)(F_HI - 1);
    const float vlA   = C_KMS * (1.0f - f0 / F_REST) - vshift;  // vlab(0)
    const float vlB   = -C_KMS * fstep / F_REST;                // vlab step / channel
    const float Dv    = 64.0f * vlB;                            // channel-64 offset
    const float c3    = 2.0f * Dv * nc2;                        // full-path delta coeffs
    const float c4    = Dv * Dv * nc2;
    const float invB  = 1.0f / vlB;
    const float cA    = -vlA * invB;                            // fc = vl*invB + cA
    // window margin: +-5.5 sigma in channel units must fit bucket slack (23.5)
    const float margin = 5.5f * lb * fabsf(invB);
    const bool  win_ok = (margin <= 23.4f);

    // ---- zero this wave's accumulators (wave-private) ----
    acc_s[col][lane]      = 0.0f;
    acc_s[col][lane + 64] = 0.0f;

    // ---- phase 1: column voxels -> bucket-classified survivors ----
    const int i = (io << 1) + (col >> 1);
    const int j = (jo << 1) + (col & 1);
    const float x  = -FOV + dx * (float)i;
    const float y  = -FOV + dx * (float)j;
    const float rx = cr * x - sr * y;          // z-independent
    const float y1 = sr * x + cr * y;
    const float ciy1 = ci * y1, siy1 = si * y1;
    const float nsvrx = -si * vmax * rx;
    const float rx2c  = rx * rx + rc2pm;
    const unsigned long long ltm = (1ull << lane) - 1ull;

    float vl_c[3], L_c[3];
    int   bk_c[3];
    #pragma unroll
    for (int c = 0; c < 3; ++c) {
        const float z  = -FOV + dx * (float)(c * 64 + lane);
        const float ry = ciy1 - si * z;
        const float rz = siy1 + ci * z;
        const float ry2 = ry * ry;
        const float R  = sqrtf(rx * rx + ry2);
        const float L  = -(R * kR + rz * rz * kz);   // log2 intensity
        const float inv  = __frsqrt_rn(ry2 + rx2c);
        const float vlos = nsvrx * inv;
        const float fc   = __builtin_fmaf(vlos, invB, cA);
        int bk = 7;                                  // 7 = dead
        if (L >= THR_L) {
            if (win_ok) {
                int k = (int)rintf((fc - 31.5f) * 0.0625f);
                bk = min(max(k, 0), 4);
            } else {
                bk = 5;                              // full-eval fallback
            }
        }
        vl_c[c] = vlos; L_c[c] = L; bk_c[c] = bk;
    }

    // pass A: per-bucket counts
    int cnt[NB];
    #pragma unroll
    for (int k = 0; k < NB; ++k) cnt[k] = 0;
    #pragma unroll
    for (int c = 0; c < 3; ++c)
        #pragma unroll
        for (int k = 0; k < NB; ++k)
            cnt[k] += __popcll(__ballot(bk_c[c] == k));

    // exact even-aligned segment bases (2 pad slots per segment)
    int base[NB];
    {
        int acc = 0;
        #pragma unroll
        for (int k = 0; k < NB; ++k) { base[k] = acc; acc += (cnt[k] + 3) & ~1; }
    }

    // pass B: scatter survivors into their segments
    {
        int run[NB];
        #pragma unroll
        for (int k = 0; k < NB; ++k) run[k] = 0;
        #pragma unroll
        for (int c = 0; c < 3; ++c)
            #pragma unroll
            for (int k = 0; k < NB; ++k) {
                const unsigned long long m = __ballot(bk_c[c] == k);
                if (bk_c[c] == k) {
                    const int pos = base[k] + run[k] + __popcll(m & ltm);
                    pairs[col][pos] = make_float2(vl_c[c], L_c[c]);
                }
                run[k] += __popcll(m);
            }
    }
    // dead pads (exp2 -> 0) so odd counts / float4 reads are safe
    #pragma unroll
    for (int k = 0; k < NB; ++k)
        if (lane < 2) pairs[col][base[k] + cnt[k] + lane] = make_float2(0.0f, -100000.0f);

    // ---- phase 2: per-bucket windowed evaluation, 1 exp/survivor/lane ----
    const float vlab0 = vlA + vlB * (float)lane;
    #pragma unroll
    for (int k = 0; k < 5; ++k) {
        const int nI = (cnt[k] + 1) >> 1;
        if (nI > 0) {
            const float4* pp = reinterpret_cast<const float4*>(&pairs[col][base[k]]);
            const float vlw = __builtin_fmaf(vlB, (float)(16 * k), vlab0); // vlab(16k+lane)
            float aw = 0.0f;
            for (int it = 0; it < nI; ++it) {
                const float4 q = pp[it];             // wave-uniform broadcast b128
                const float dA = vlw - q.x;
                const float dB = vlw - q.z;
                aw += fast_exp2(__builtin_fmaf(dA, dA * nc2, q.y));
                aw += fast_exp2(__builtin_fmaf(dB, dB * nc2, q.w));
            }
            acc_s[col][16 * k + lane] += aw;         // stride-1, conflict-free
        }
    }
    // bucket 5: full 128-channel path (only if margin didn't fit; empty at lb=20)
    {
        const int nI = (cnt[5] + 1) >> 1;
        if (nI > 0) {
            const float4* pp = reinterpret_cast<const float4*>(&pairs[col][base[5]]);
            float a0 = 0.0f, a1 = 0.0f;
            for (int it = 0; it < nI; ++it) {
                const float4 q = pp[it];
                {
                    const float d0   = vlab0 - q.x;
                    const float arg0 = __builtin_fmaf(d0, d0 * nc2, q.y);
                    a0 += fast_exp2(arg0);
                    a1 += fast_exp2(arg0 + __builtin_fmaf(d0, c3, c4));
                }
                {
                    const float d0   = vlab0 - q.z;
                    const float arg0 = __builtin_fmaf(d0, d0 * nc2, q.w);
                    a0 += fast_exp2(arg0);
                    a1 += fast_exp2(arg0 + __builtin_fmaf(d0, c3, c4));
                }
            }
            acc_s[col][lane]      += a0;
            acc_s[col][lane + 64] += a1;
        }
    }
    __syncthreads();

    // ---- phase 3: fold 4 cols x 4 freq-subchannels -> 32 outputs ----
    if (tid < FOUT) {
        float s = 0.0f;
        #pragma unroll
        for (int fu = 0; fu < 4; ++fu)
            #pragma unroll
            for (int c2 = 0; c2 < 4; ++c2)
                s += acc_s[c2][4 * tid + fu];
        const float norm16 = (1.0f / sqrtf(2.0f * 3.14159265358979f * sig_sq)) / 16.0f;
        out[tid * (NOUT * NOUT) + io * NOUT + jo] = s * norm16;
    }
}

extern "C" void kernel_launch(void* const* d_in, const int* in_sizes, int n_in,
                              void* d_out, int out_size, void* d_ws, size_t ws_size,
                              hipStream_t stream) {
    const float* p_inc  = (const float*)d_in[0];
    const float* p_rot  = (const float*)d_in[1];
    const float* p_lb   = (const float*)d_in[2];
    const float* p_vs   = (const float*)d_in[3];
    const float* p_vmax = (const float*)d_in[4];
    const float* p_rc   = (const float*)d_in[5];
    const float* p_Rd   = (const float*)d_in[6];
    const float* p_hz   = (const float*)d_in[7];
    const float* freqs  = (const float*)d_in[8];
    float* out = (float*)d_out;

    dim3 grid(NOUT, NOUT);
    dim3 block(256);
    cube_sim_kernel<<<grid, block, 0, stream>>>(p_inc, p_rot, p_lb, p_vs,
                                                p_vmax, p_rc, p_Rd, p_hz,
                                                freqs, out);
}